// Round 4
// baseline (684.563 us; speedup 1.0000x reference)
//
#include <hip/hip_runtime.h>
#include <cstdint>

typedef unsigned short u16;
typedef unsigned long long u64;
typedef short short8 __attribute__((ext_vector_type(8)));
typedef float f32x4 __attribute__((ext_vector_type(4)));

#define D_DIM 192
#define M_PROT 128
#define KCOLS 256
#define GRID_P 512
#define GRID_S 1024
#define GRID_P4 512
#define BLK 1024
#define CHUNK_ROWS 64
#define XSTRIDE 200   // u16 per x-row in LDS; 100 dwords -> 2-way banks on b128 reads (free)
#define NROWS_MAX 131072

// Materialized E = exp(20 * cos_sim) matrix, row-major [N][256]. 128 MiB static
// device allocation (fits Infinity Cache; avoids ws_size assumptions, graph-safe).
__device__ float Ebuf[(size_t)NROWS_MAX * KCOLS];
// Per-block column partials (static so grid sizes aren't limited by ws_size).
__device__ float Pbuf[(size_t)1024 * KCOLS];

__device__ __forceinline__ float newton_rsqrt(float ss) {
    float m = fmaxf(ss, 1e-12f);
    float r = rsqrtf(m);
    r = r * (1.5f - 0.5f * m * r * r);
    return r;
}
__device__ __forceinline__ float fast_rcp(float x) {
    float r = __builtin_amdgcn_rcpf(x);
    return r * (2.0f - x * r);
}
// split fp32 -> bf16 hi (RNE) + bf16 lo (trunc of exact residual)
__device__ __forceinline__ void split1(float f, uint32_t& h, uint32_t& l) {
    uint32_t u = __float_as_uint(f);
    uint32_t uh = (u + 0x7FFFu + ((u >> 16) & 1u)) & 0xFFFF0000u;
    h = uh >> 16;
    l = __float_as_uint(f - __uint_as_float(uh)) >> 16;
}

// ---------------------------------------------------------------------------
__global__ void prep_kern(const float* __restrict__ lp, const float* __restrict__ gp,
                          u16* __restrict__ phi, u16* __restrict__ plo,
                          float* __restrict__ invnp, int* __restrict__ lastIdx) {
    int r = blockIdx.x, j = threadIdx.x;  // 256 x 64
    const float* src = (r < M_PROT) ? (lp + r * D_DIM) : (gp + (r - M_PROT) * D_DIM);
    float ss = 0.0f;
    for (int c = j; c < D_DIM; c += 64) {
        float f = src[c];
        ss = fmaf(f, f, ss);
        uint32_t h, l;
        split1(f, h, l);
        phi[r * D_DIM + c] = (u16)h;
        plo[r * D_DIM + c] = (u16)l;
    }
#pragma unroll
    for (int m = 1; m <= 32; m <<= 1) ss += __shfl_xor(ss, m);
    if (j == 0) {
        invnp[r] = newton_rsqrt(ss);
        if (r < M_PROT) lastIdx[r] = -1;
    }
}

// ---------------------------------------------------------------------------
__global__ __launch_bounds__(384) void glu_kern(const float* __restrict__ gp,
                                                const float* __restrict__ W,
                                                const float* __restrict__ b,
                                                float* __restrict__ gated) {
    __shared__ float grow[D_DIM];
    __shared__ float lin[2 * D_DIM];
    int m = blockIdx.x, j = threadIdx.x;
    if (j < D_DIM) grow[j] = gp[m * D_DIM + j];
    __syncthreads();
    float a = b[j];
    for (int k = 0; k < D_DIM; k++) a = fmaf(grow[k], W[k * 2 * D_DIM + j], a);
    lin[j] = a;
    __syncthreads();
    if (j < D_DIM) {
        float g = lin[j] * (1.0f / (1.0f + __expf(-lin[j + D_DIM])));
        gated[m * D_DIM + j] = g;
    }
}

// ---------------------------------------------------------------------------
__global__ __launch_bounds__(1024) void reduce_cols(float* __restrict__ outf, int G) {
    __shared__ float acc[4][KCOLS];
    int j = threadIdx.x & 255;
    int sl = threadIdx.x >> 8;
    float s = 0.0f;
    for (int g = sl; g < G; g += 4) s += Pbuf[g * KCOLS + j];
    acc[sl][j] = s;
    __syncthreads();
    if (threadIdx.x < KCOLS) {
        int jj = threadIdx.x;
        outf[jj] = 1.0f / (acc[0][jj] + acc[1][jj] + acc[2][jj] + acc[3][jj]);
    }
}

// ---------------------------------------------------------------------------
// Pass 1: MFMA similarity + E = exp(20*sim) computed once, STORED to Ebuf,
// plus fused rowsum/colsum-1 epilogue (identical numerics to prior PASS=1).
__global__ __launch_bounds__(BLK, 4) void pass1_kern(
    const float* __restrict__ x, const uint4* __restrict__ phiv, const uint4* __restrict__ plov,
    const float* __restrict__ invnp, int nchunks) {
    __shared__ u16 xhiS[CHUNK_ROWS * XSTRIDE];
    __shared__ u16 xloS[CHUNK_ROWS * XSTRIDE];
    __shared__ float xss[CHUNK_ROWS];
    __shared__ float rsum[2][CHUNK_ROWS];

    const int tid = threadIdx.x;
    const int lane = tid & 63;
    const int wave = tid >> 6;        // 0..15: proto col-tile
    const int quad = lane >> 4;
    const int lcol = lane & 15;
    const int srow = tid >> 4;        // staging: row 0..63
    const int scg = tid & 15;         // staging: col-group (12 floats)

    // --- B fragments in registers: this wave's 16 proto cols, all K, hi+lo ---
    uint4 Bhi[6], Blo[6];
    {
        int prow = wave * 16 + lcol;
#pragma unroll
        for (int kk = 0; kk < 6; kk++) {
            int idx = prow * 24 + kk * 4 + quad;
            Bhi[kk] = phiv[idx];
            Blo[kk] = plov[idx];
        }
    }
    const float pnf = invnp[wave * 16 + lcol];
    float colpart = 0.0f;

    // prefetch chunk 0: 3 float4 = 12 contiguous cols of row srow
    float4 st[3];
    int chunk = blockIdx.x;
    if (chunk < nchunks) {
        const float4* src = (const float4*)(x + (size_t)chunk * CHUNK_ROWS * D_DIM +
                                            srow * D_DIM + scg * 12);
#pragma unroll
        for (int j = 0; j < 3; j++) st[j] = src[j];
    }

    int it = 0;
    for (; chunk < nchunks; chunk += gridDim.x, it++) {
        const int p = it & 1;
        if (tid < CHUNK_ROWS) rsum[p][tid] = 0.0f;
        {
            float ssq = 0.0f;
            u16* bh = xhiS + srow * XSTRIDE + scg * 12;
            u16* bl = xloS + srow * XSTRIDE + scg * 12;
#pragma unroll
            for (int j = 0; j < 3; j++) {
                float4 v = st[j];
                ssq = fmaf(v.x, v.x, ssq);
                ssq = fmaf(v.y, v.y, ssq);
                ssq = fmaf(v.z, v.z, ssq);
                ssq = fmaf(v.w, v.w, ssq);
                uint32_t h0, l0, h1, l1, h2, l2, h3, l3;
                split1(v.x, h0, l0); split1(v.y, h1, l1);
                split1(v.z, h2, l2); split1(v.w, h3, l3);
                uint2 hp = {h0 | (h1 << 16), h2 | (h3 << 16)};
                uint2 lq = {l0 | (l1 << 16), l2 | (l3 << 16)};
                *(uint2*)(bh + j * 4) = hp;
                *(uint2*)(bl + j * 4) = lq;
            }
            ssq += __shfl_xor(ssq, 1);
            ssq += __shfl_xor(ssq, 2);
            ssq += __shfl_xor(ssq, 4);
            ssq += __shfl_xor(ssq, 8);
            if (scg == 0) xss[srow] = ssq;
        }
        {   // prefetch next chunk while this one computes
            int nc = chunk + gridDim.x;
            if (nc < nchunks) {
                const float4* src = (const float4*)(x + (size_t)nc * CHUNK_ROWS * D_DIM +
                                                    srow * D_DIM + scg * 12);
#pragma unroll
                for (int j = 0; j < 3; j++) st[j] = src[j];
            }
        }
        __syncthreads();  // S_b: staging visible

        f32x4 E[4];
#pragma unroll
        for (int s = 0; s < 4; s++) {
            f32x4 a0 = {}, a1 = {};
#pragma unroll
            for (int kk = 0; kk < 6; kk++) {
                int off = (s * 16 + lcol) * XSTRIDE + kk * 32 + quad * 8;
                uint4 hraw = *(const uint4*)(xhiS + off);
                uint4 lraw = *(const uint4*)(xloS + off);
                short8 ah = __builtin_bit_cast(short8, hraw);
                short8 al = __builtin_bit_cast(short8, lraw);
                short8 bh = __builtin_bit_cast(short8, Bhi[kk]);
                short8 bl = __builtin_bit_cast(short8, Blo[kk]);
                if (kk & 1) {
                    a1 = __builtin_amdgcn_mfma_f32_16x16x32_bf16(ah, bh, a1, 0, 0, 0);
                    a1 = __builtin_amdgcn_mfma_f32_16x16x32_bf16(ah, bl, a1, 0, 0, 0);
                    a1 = __builtin_amdgcn_mfma_f32_16x16x32_bf16(al, bh, a1, 0, 0, 0);
                } else {
                    a0 = __builtin_amdgcn_mfma_f32_16x16x32_bf16(ah, bh, a0, 0, 0, 0);
                    a0 = __builtin_amdgcn_mfma_f32_16x16x32_bf16(ah, bl, a0, 0, 0, 0);
                    a0 = __builtin_amdgcn_mfma_f32_16x16x32_bf16(al, bh, a0, 0, 0, 0);
                }
            }
            const int rowb = s * 16 + quad * 4;
#pragma unroll
            for (int r = 0; r < 4; r++) {
                float invnx = newton_rsqrt(xss[rowb + r]);
                E[s][r] = __expf((a0[r] + a1[r]) * invnx * pnf * 20.0f);
            }
            // store E tile to global (row-major [N][256]); fire-and-forget
            {
                float* eb = Ebuf + ((size_t)chunk * CHUNK_ROWS + rowb) * KCOLS +
                            (wave * 16 + lcol);
#pragma unroll
                for (int r = 0; r < 4; r++) eb[r * KCOLS] = E[s][r];
            }
#pragma unroll
            for (int r = 0; r < 4; r++) {
                float pe = E[s][r];
                pe += __shfl_xor(pe, 1);
                pe += __shfl_xor(pe, 2);
                pe += __shfl_xor(pe, 4);
                pe += __shfl_xor(pe, 8);
                if (lcol == 0) atomicAdd(&rsum[p][rowb + r], pe);
            }
        }
        __syncthreads();  // S_c: rsum complete

#pragma unroll
        for (int s = 0; s < 4; s++) {
            const int rowb = s * 16 + quad * 4;
#pragma unroll
            for (int r = 0; r < 4; r++) {
                float rv = fast_rcp(rsum[p][rowb + r]);
                colpart = fmaf(E[s][r], rv, colpart);
            }
        }
    }

    colpart += __shfl_xor(colpart, 16);
    colpart += __shfl_xor(colpart, 32);
    if (lane < 16) Pbuf[blockIdx.x * KCOLS + wave * 16 + lcol] = colpart;
}

// ---------------------------------------------------------------------------
// Sinkhorn iteration, chunk-cooperative: block loads 64x256 E chunk coalesced
// (thread t owns row t>>4, cols (t&15)*16..+15), reg-dbuf prefetch, 4-shuffle
// row reduce within 16-lane subgroup. Same telescoping convention as before.
__global__ __launch_bounds__(1024) void sink_chunk(const float* __restrict__ w,
                                                   int nchunks) {
    __shared__ float acc[KCOLS];
    const int tid = threadIdx.x;
    const int cg = tid & 15;
    if (tid < KCOLS) acc[tid] = 0.0f;

    float4 wv[4];
    {
        const float4* wvp = (const float4*)w;
#pragma unroll
        for (int k = 0; k < 4; k++) wv[k] = wvp[cg * 4 + k];
    }
    float4 cp[4];
#pragma unroll
    for (int k = 0; k < 4; k++) { cp[k].x = 0.f; cp[k].y = 0.f; cp[k].z = 0.f; cp[k].w = 0.f; }

    int chunk = blockIdx.x;
    float4 st[4];
    if (chunk < nchunks) {
        const float4* src = (const float4*)(Ebuf + (size_t)chunk * CHUNK_ROWS * KCOLS) + tid * 4;
#pragma unroll
        for (int k = 0; k < 4; k++) st[k] = src[k];
    }

    for (; chunk < nchunks; chunk += gridDim.x) {
        // row-sum partial over this thread's 16 cols
        float rs = 0.0f;
#pragma unroll
        for (int k = 0; k < 4; k++) {
            rs = fmaf(st[k].x, wv[k].x, rs);
            rs = fmaf(st[k].y, wv[k].y, rs);
            rs = fmaf(st[k].z, wv[k].z, rs);
            rs = fmaf(st[k].w, wv[k].w, rs);
        }
        // prefetch next chunk into separate regs (uniform guard)
        const int nc = chunk + gridDim.x;
        float4 nx[4];
        if (nc < nchunks) {
            const float4* src = (const float4*)(Ebuf + (size_t)nc * CHUNK_ROWS * KCOLS) + tid * 4;
#pragma unroll
            for (int k = 0; k < 4; k++) nx[k] = src[k];
        }
        // reduce across the 16 threads owning this row (lanes grouped by 16)
        rs += __shfl_xor(rs, 1);
        rs += __shfl_xor(rs, 2);
        rs += __shfl_xor(rs, 4);
        rs += __shfl_xor(rs, 8);
        const float rv = fast_rcp(rs);
#pragma unroll
        for (int k = 0; k < 4; k++) {
            cp[k].x = fmaf(st[k].x, rv, cp[k].x);
            cp[k].y = fmaf(st[k].y, rv, cp[k].y);
            cp[k].z = fmaf(st[k].z, rv, cp[k].z);
            cp[k].w = fmaf(st[k].w, rv, cp[k].w);
        }
        if (nc < nchunks) {
#pragma unroll
            for (int k = 0; k < 4; k++) st[k] = nx[k];
        }
    }

    __syncthreads();  // acc init visible
#pragma unroll
    for (int k = 0; k < 4; k++) {
        atomicAdd(&acc[cg * 16 + k * 4 + 0], cp[k].x);
        atomicAdd(&acc[cg * 16 + k * 4 + 1], cp[k].y);
        atomicAdd(&acc[cg * 16 + k * 4 + 2], cp[k].z);
        atomicAdd(&acc[cg * 16 + k * 4 + 3], cp[k].w);
    }
    __syncthreads();
    if (tid < KCOLS) Pbuf[blockIdx.x * KCOLS + tid] = acc[tid];
}

// ---------------------------------------------------------------------------
// Final pass, chunk-cooperative: coalesced E chunk loads + reg dbuf; per-row
// argmax via 3 subgroup shuffles + plain LDS store (no atomics); lastIdx
// pre-reduced per-block in LDS; epilogue = 4 independent rows per wave.
__global__ __launch_bounds__(1024) void pass4_chunk(const float* __restrict__ g3,
                                                    const float* __restrict__ x,
                                                    const float* __restrict__ gated,
                                                    int* __restrict__ lastIdx,
                                                    float* __restrict__ outp, int nchunks) {
    __shared__ u64 bestL[2][CHUNK_ROWS];
    __shared__ u64 bestG[2][CHUNK_ROWS];
    __shared__ int blkBest[M_PROT];

    const int tid = threadIdx.x;
    const int lane = tid & 63;
    const int wave = tid >> 6;
    const int r16 = tid >> 4;   // row within chunk
    const int cg = tid & 15;    // col-group: cols cg*16..cg*16+15

    if (tid < M_PROT) blkBest[tid] = -1;

    float4 cf[4];
    {
        const float4* g3v = (const float4*)g3;
#pragma unroll
        for (int k = 0; k < 4; k++) cf[k] = g3v[cg * 4 + k];
    }

    int chunk = blockIdx.x;
    float4 st[4];
    if (chunk < nchunks) {
        const float4* src = (const float4*)(Ebuf + (size_t)chunk * CHUNK_ROWS * KCOLS) + tid * 4;
#pragma unroll
        for (int k = 0; k < 4; k++) st[k] = src[k];
    }
    __syncthreads();  // blkBest init visible

    int it = 0;
    for (; chunk < nchunks; chunk += gridDim.x, it++) {
        const int p = it & 1;
        // build this thread's best key over its 16 cols
        u64 key = 0;
        const int cb = cg * 16;
#pragma unroll
        for (int k = 0; k < 4; k++) {
            const float* ek = (const float*)&st[k];
            const float* ck = (const float*)&cf[k];
#pragma unroll
            for (int j = 0; j < 4; j++) {
                float v = ek[j] * ck[j];
                u64 kk = ((u64)__float_as_uint(v) << 32) | (u64)(255 - (cb + k * 4 + j));
                if (kk > key) key = kk;
            }
        }
        // prefetch next chunk (st fully consumed above; uniform guard)
        {
            int nc = chunk + gridDim.x;
            if (nc < nchunks) {
                const float4* src = (const float4*)(Ebuf + (size_t)nc * CHUNK_ROWS * KCOLS) + tid * 4;
#pragma unroll
                for (int k = 0; k < 4; k++) st[k] = src[k];
            }
        }
        // reduce within 8-lane half-group (cg 0..7 = local cols, 8..15 = global)
        {
            u64 ok;
            ok = __shfl_xor((unsigned long long)key, 1); if (ok > key) key = ok;
            ok = __shfl_xor((unsigned long long)key, 2); if (ok > key) key = ok;
            ok = __shfl_xor((unsigned long long)key, 4); if (ok > key) key = ok;
        }
        if ((lane & 7) == 0) {
            if (cg < 8) bestL[p][r16] = key;
            else bestG[p][r16] = key;
        }
        __syncthreads();  // bests visible (parity reuse at distance 2 is fenced
                          // by the NEXT iteration's barrier before overwrite)

        if (tid < CHUNK_ROWS) {
            int colL = 255 - (int)(bestL[p][tid] & 0xFFFFFFFFull);
            atomicMax(&blkBest[colL], chunk * CHUNK_ROWS + tid);  // LDS atomic
        }
#pragma unroll
        for (int rr = 0; rr < 4; rr++) {
            const int row = wave * 4 + rr;
            const int grow = chunk * CHUNK_ROWS + row;
            const float* xr = x + (size_t)grow * D_DIM;
            float x0 = xr[lane];
            float x1 = xr[lane + 64];
            float x2 = xr[lane + 128];
            const int ga = (255 - (int)(bestG[p][row] & 0xFFFFFFFFull)) - 128;
            const float* gr = gated + ga * D_DIM;
            float v0 = 0.5f * (gr[lane] + x0);
            float v1 = 0.5f * (gr[lane + 64] + x1);
            float v2 = 0.5f * (gr[lane + 128] + x2);
            float ss = v0 * v0;
            ss = fmaf(v1, v1, ss);
            ss = fmaf(v2, v2, ss);
            ss += __shfl_xor(ss, 1);
            ss += __shfl_xor(ss, 2);
            ss += __shfl_xor(ss, 4);
            ss += __shfl_xor(ss, 8);
            ss += __shfl_xor(ss, 16);
            ss += __shfl_xor(ss, 32);
            const float sc = newton_rsqrt(ss);
            float* orow = outp + (size_t)grow * D_DIM;
            orow[lane] = v0 * sc;
            orow[lane + 64] = v1 * sc;
            orow[lane + 128] = v2 * sc;
        }
    }

    __syncthreads();
    if (tid < M_PROT) {
        int b = blkBest[tid];
        if (b >= 0) atomicMax(&lastIdx[tid], b);
    }
}

// ---------------------------------------------------------------------------
__global__ void final_local(const float* __restrict__ lp, const float* __restrict__ x,
                            const int* __restrict__ lastIdx, float* __restrict__ outL) {
    int m = blockIdx.x;   // 128
    int c = threadIdx.x;  // 192
    int idx = lastIdx[m];
    float v = lp[m * D_DIM + c];
    if (idx >= 0) v = 0.96f * v + (float)(1.0 - 0.96) * x[(size_t)idx * D_DIM + c];
    outL[m * D_DIM + c] = v;
}

// ---------------------------------------------------------------------------
extern "C" void kernel_launch(void* const* d_in, const int* in_sizes, int n_in,
                              void* d_out, int out_size, void* d_ws, size_t ws_size,
                              hipStream_t stream) {
    const float* x = (const float*)d_in[0];
    const float* lp = (const float*)d_in[1];
    const float* gp = (const float*)d_in[2];
    const float* W = (const float*)d_in[3];
    const float* b = (const float*)d_in[4];
    float* out = (float*)d_out;
    const int nrows = in_sizes[0] / D_DIM;  // 131072
    const int nchunks = nrows / CHUNK_ROWS; // 2048

    char* wsb = (char*)d_ws;
    float* invnp = (float*)(wsb + 0);
    float* g1 = (float*)(wsb + 1024);
    float* g2 = (float*)(wsb + 2048);
    float* g3 = (float*)(wsb + 3072);
    int* lastIdx = (int*)(wsb + 4096);
    float* gated = (float*)(wsb + 8192);      // 128*192 f
    u16* phi = (u16*)(wsb + 106496);          // 256*192 u16
    u16* plo = (u16*)(wsb + 204800);          // 256*192 u16

    const uint4* phiv = (const uint4*)phi;
    const uint4* plov = (const uint4*)plo;

    prep_kern<<<256, 64, 0, stream>>>(lp, gp, phi, plo, invnp, lastIdx);
    glu_kern<<<128, 384, 0, stream>>>(gp, W, b, gated);
    pass1_kern<<<GRID_P, BLK, 0, stream>>>(x, phiv, plov, invnp, nchunks);
    reduce_cols<<<1, 1024, 0, stream>>>(g1, GRID_P);
    sink_chunk<<<GRID_S, BLK, 0, stream>>>(g1, nchunks);
    reduce_cols<<<1, 1024, 0, stream>>>(g2, GRID_S);
    sink_chunk<<<GRID_S, BLK, 0, stream>>>(g2, nchunks);
    reduce_cols<<<1, 1024, 0, stream>>>(g3, GRID_S);
    pass4_chunk<<<GRID_P4, BLK, 0, stream>>>(g3, x, gated, lastIdx, out, nchunks);
    final_local<<<128, 192, 0, stream>>>(lp, x, lastIdx, out + (size_t)nrows * D_DIM);
}

// Round 6
// 427.007 us; speedup vs baseline: 1.6032x; 1.6032x over previous
//
#include <hip/hip_runtime.h>
#include <cstdint>

typedef unsigned short u16;
typedef unsigned long long u64;
typedef short short8 __attribute__((ext_vector_type(8)));
typedef float f32x4 __attribute__((ext_vector_type(4)));

#define D_DIM 192
#define M_PROT 128
#define KCOLS 256
#define GRID_P 256      // pass1: 1024-thr blocks -> 1/CU; grid = CU count
#define GRID_SL 2048    // slab kernels: 256-thr blocks, 8/CU target
#define BLK 1024
#define CHUNK_ROWS 64
#define SLAB_ROWS 16
#define XSTRIDE 200   // u16 per x-row in LDS; 100 dwords -> 2-way banks on b128 reads (free)
#define NROWS_MAX 131072
#define RED1_BLKS 64

// Materialized E = exp(20 * cos_sim) matrix, row-major [N][256]. 128 MiB static
// device allocation (fits Infinity Cache; avoids ws_size assumptions, graph-safe).
__device__ float Ebuf[(size_t)NROWS_MAX * KCOLS];
// Per-block column partials + two-stage reduce intermediate.
__device__ float Pbuf[(size_t)GRID_SL * KCOLS];
__device__ float Mbuf[(size_t)RED1_BLKS * KCOLS];
// Per-block local-argmax "last row index" candidates (merged in final_local).
__device__ int Bbuf[(size_t)GRID_SL * M_PROT];

__device__ __forceinline__ float newton_rsqrt(float ss) {
    float m = fmaxf(ss, 1e-12f);
    float r = rsqrtf(m);
    r = r * (1.5f - 0.5f * m * r * r);
    return r;
}
__device__ __forceinline__ float fast_rcp(float x) {
    float r = __builtin_amdgcn_rcpf(x);
    return r * (2.0f - x * r);
}
// split fp32 -> bf16 hi (RNE) + bf16 lo (trunc of exact residual)
__device__ __forceinline__ void split1(float f, uint32_t& h, uint32_t& l) {
    uint32_t u = __float_as_uint(f);
    uint32_t uh = (u + 0x7FFFu + ((u >> 16) & 1u)) & 0xFFFF0000u;
    h = uh >> 16;
    l = __float_as_uint(f - __uint_as_float(uh)) >> 16;
}

// ---------------------------------------------------------------------------
__global__ void prep_kern(const float* __restrict__ lp, const float* __restrict__ gp,
                          u16* __restrict__ phi, u16* __restrict__ plo,
                          float* __restrict__ invnp) {
    int r = blockIdx.x, j = threadIdx.x;  // 256 x 64
    const float* src = (r < M_PROT) ? (lp + r * D_DIM) : (gp + (r - M_PROT) * D_DIM);
    float ss = 0.0f;
    for (int c = j; c < D_DIM; c += 64) {
        float f = src[c];
        ss = fmaf(f, f, ss);
        uint32_t h, l;
        split1(f, h, l);
        phi[r * D_DIM + c] = (u16)h;
        plo[r * D_DIM + c] = (u16)l;
    }
#pragma unroll
    for (int m = 1; m <= 32; m <<= 1) ss += __shfl_xor(ss, m);
    if (j == 0) invnp[r] = newton_rsqrt(ss);
}

// ---------------------------------------------------------------------------
__global__ __launch_bounds__(384) void glu_kern(const float* __restrict__ gp,
                                                const float* __restrict__ W,
                                                const float* __restrict__ b,
                                                float* __restrict__ gated) {
    __shared__ float grow[D_DIM];
    __shared__ float lin[2 * D_DIM];
    int m = blockIdx.x, j = threadIdx.x;
    if (j < D_DIM) grow[j] = gp[m * D_DIM + j];
    __syncthreads();
    float a = b[j];
    for (int k = 0; k < D_DIM; k++) a = fmaf(grow[k], W[k * 2 * D_DIM + j], a);
    lin[j] = a;
    __syncthreads();
    if (j < D_DIM) {
        float g = lin[j] * (1.0f / (1.0f + __expf(-lin[j + D_DIM])));
        gated[m * D_DIM + j] = g;
    }
}

// ---------------------------------------------------------------------------
// Two-stage parallel column reduce: Pbuf[0..G) -> Mbuf[64] -> outf (1/x).
__global__ __launch_bounds__(256) void reduce1(int G) {
    int j = threadIdx.x;
    float s = 0.0f;
    for (int g = blockIdx.x; g < G; g += RED1_BLKS) s += Pbuf[(size_t)g * KCOLS + j];
    Mbuf[blockIdx.x * KCOLS + j] = s;
}
__global__ __launch_bounds__(256) void reduce2(float* __restrict__ outf) {
    int j = threadIdx.x;
    float s = 0.0f;
    for (int g = 0; g < RED1_BLKS; g++) s += Mbuf[g * KCOLS + j];
    outf[j] = 1.0f / s;
}

// ---------------------------------------------------------------------------
// Pass 1: MFMA similarity + E = exp(20*sim) computed once, STORED to Ebuf,
// plus fused rowsum/colsum-1 epilogue (identical numerics to prior PASS=1).
__global__ __launch_bounds__(BLK, 4) void pass1_kern(
    const float* __restrict__ x, const uint4* __restrict__ phiv, const uint4* __restrict__ plov,
    const float* __restrict__ invnp, int nchunks) {
    __shared__ u16 xhiS[CHUNK_ROWS * XSTRIDE];
    __shared__ u16 xloS[CHUNK_ROWS * XSTRIDE];
    __shared__ float xss[CHUNK_ROWS];
    __shared__ float rsum[2][CHUNK_ROWS];

    const int tid = threadIdx.x;
    const int lane = tid & 63;
    const int wave = tid >> 6;        // 0..15: proto col-tile
    const int quad = lane >> 4;
    const int lcol = lane & 15;
    const int srow = tid >> 4;        // staging: row 0..63
    const int scg = tid & 15;         // staging: col-group (12 floats)

    // --- B fragments in registers: this wave's 16 proto cols, all K, hi+lo ---
    uint4 Bhi[6], Blo[6];
    {
        int prow = wave * 16 + lcol;
#pragma unroll
        for (int kk = 0; kk < 6; kk++) {
            int idx = prow * 24 + kk * 4 + quad;
            Bhi[kk] = phiv[idx];
            Blo[kk] = plov[idx];
        }
    }
    const float pnf = invnp[wave * 16 + lcol];
    float colpart = 0.0f;

    // prefetch chunk 0: 3 float4 = 12 contiguous cols of row srow
    float4 st[3];
    int chunk = blockIdx.x;
    if (chunk < nchunks) {
        const float4* src = (const float4*)(x + (size_t)chunk * CHUNK_ROWS * D_DIM +
                                            srow * D_DIM + scg * 12);
#pragma unroll
        for (int j = 0; j < 3; j++) st[j] = src[j];
    }

    int it = 0;
    for (; chunk < nchunks; chunk += gridDim.x, it++) {
        const int p = it & 1;
        if (tid < CHUNK_ROWS) rsum[p][tid] = 0.0f;
        {
            float ssq = 0.0f;
            u16* bh = xhiS + srow * XSTRIDE + scg * 12;
            u16* bl = xloS + srow * XSTRIDE + scg * 12;
#pragma unroll
            for (int j = 0; j < 3; j++) {
                float4 v = st[j];
                ssq = fmaf(v.x, v.x, ssq);
                ssq = fmaf(v.y, v.y, ssq);
                ssq = fmaf(v.z, v.z, ssq);
                ssq = fmaf(v.w, v.w, ssq);
                uint32_t h0, l0, h1, l1, h2, l2, h3, l3;
                split1(v.x, h0, l0); split1(v.y, h1, l1);
                split1(v.z, h2, l2); split1(v.w, h3, l3);
                uint2 hp = {h0 | (h1 << 16), h2 | (h3 << 16)};
                uint2 lq = {l0 | (l1 << 16), l2 | (l3 << 16)};
                *(uint2*)(bh + j * 4) = hp;
                *(uint2*)(bl + j * 4) = lq;
            }
            ssq += __shfl_xor(ssq, 1);
            ssq += __shfl_xor(ssq, 2);
            ssq += __shfl_xor(ssq, 4);
            ssq += __shfl_xor(ssq, 8);
            if (scg == 0) xss[srow] = ssq;
        }
        {   // prefetch next chunk while this one computes
            int nc = chunk + gridDim.x;
            if (nc < nchunks) {
                const float4* src = (const float4*)(x + (size_t)nc * CHUNK_ROWS * D_DIM +
                                                    srow * D_DIM + scg * 12);
#pragma unroll
                for (int j = 0; j < 3; j++) st[j] = src[j];
            }
        }
        __syncthreads();  // S_b: staging visible

        f32x4 E[4];
#pragma unroll
        for (int s = 0; s < 4; s++) {
            f32x4 a0 = {}, a1 = {};
#pragma unroll
            for (int kk = 0; kk < 6; kk++) {
                int off = (s * 16 + lcol) * XSTRIDE + kk * 32 + quad * 8;
                uint4 hraw = *(const uint4*)(xhiS + off);
                uint4 lraw = *(const uint4*)(xloS + off);
                short8 ah = __builtin_bit_cast(short8, hraw);
                short8 al = __builtin_bit_cast(short8, lraw);
                short8 bh = __builtin_bit_cast(short8, Bhi[kk]);
                short8 bl = __builtin_bit_cast(short8, Blo[kk]);
                if (kk & 1) {
                    a1 = __builtin_amdgcn_mfma_f32_16x16x32_bf16(ah, bh, a1, 0, 0, 0);
                    a1 = __builtin_amdgcn_mfma_f32_16x16x32_bf16(ah, bl, a1, 0, 0, 0);
                    a1 = __builtin_amdgcn_mfma_f32_16x16x32_bf16(al, bh, a1, 0, 0, 0);
                } else {
                    a0 = __builtin_amdgcn_mfma_f32_16x16x32_bf16(ah, bh, a0, 0, 0, 0);
                    a0 = __builtin_amdgcn_mfma_f32_16x16x32_bf16(ah, bl, a0, 0, 0, 0);
                    a0 = __builtin_amdgcn_mfma_f32_16x16x32_bf16(al, bh, a0, 0, 0, 0);
                }
            }
            const int rowb = s * 16 + quad * 4;
#pragma unroll
            for (int r = 0; r < 4; r++) {
                float invnx = newton_rsqrt(xss[rowb + r]);
                E[s][r] = __expf((a0[r] + a1[r]) * invnx * pnf * 20.0f);
            }
            // store E tile to global (row-major [N][256]); fire-and-forget
            {
                float* eb = Ebuf + ((size_t)chunk * CHUNK_ROWS + rowb) * KCOLS +
                            (wave * 16 + lcol);
#pragma unroll
                for (int r = 0; r < 4; r++) eb[r * KCOLS] = E[s][r];
            }
#pragma unroll
            for (int r = 0; r < 4; r++) {
                float pe = E[s][r];
                pe += __shfl_xor(pe, 1);
                pe += __shfl_xor(pe, 2);
                pe += __shfl_xor(pe, 4);
                pe += __shfl_xor(pe, 8);
                if (lcol == 0) atomicAdd(&rsum[p][rowb + r], pe);
            }
        }
        __syncthreads();  // S_c: rsum complete

#pragma unroll
        for (int s = 0; s < 4; s++) {
            const int rowb = s * 16 + quad * 4;
#pragma unroll
            for (int r = 0; r < 4; r++) {
                float rv = fast_rcp(rsum[p][rowb + r]);
                colpart = fmaf(E[s][r], rv, colpart);
            }
        }
    }

    colpart += __shfl_xor(colpart, 16);
    colpart += __shfl_xor(colpart, 32);
    if (lane < 16) Pbuf[(size_t)blockIdx.x * KCOLS + wave * 16 + lcol] = colpart;
}

// ---------------------------------------------------------------------------
// Sinkhorn iteration, slab-cooperative 256-thr blocks (4 waves -> packs 8/CU).
// Thread t owns row t>>4 of the slab, cols (t&15)*16..+15. No prefetch (TLP
// from block-level parallelism hides latency; keeps VGPR < 64).
__global__ __launch_bounds__(256) void sink_slab(const float* __restrict__ w,
                                                 int nslabs) {
    __shared__ float acc[KCOLS];
    const int tid = threadIdx.x;
    const int cg = tid & 15;
    acc[tid] = 0.0f;

    float4 wv[4];
    {
        const float4* wvp = (const float4*)w;
#pragma unroll
        for (int k = 0; k < 4; k++) wv[k] = wvp[cg * 4 + k];
    }
    float4 cp[4];
#pragma unroll
    for (int k = 0; k < 4; k++) { cp[k].x = 0.f; cp[k].y = 0.f; cp[k].z = 0.f; cp[k].w = 0.f; }

    for (int slab = blockIdx.x; slab < nslabs; slab += gridDim.x) {
        float4 st[4];
        const float4* src = (const float4*)(Ebuf + (size_t)slab * SLAB_ROWS * KCOLS) + tid * 4;
#pragma unroll
        for (int k = 0; k < 4; k++) st[k] = src[k];

        float rs = 0.0f;
#pragma unroll
        for (int k = 0; k < 4; k++) {
            rs = fmaf(st[k].x, wv[k].x, rs);
            rs = fmaf(st[k].y, wv[k].y, rs);
            rs = fmaf(st[k].z, wv[k].z, rs);
            rs = fmaf(st[k].w, wv[k].w, rs);
        }
        // reduce across the 16 threads owning this row (16-lane subgroups)
        rs += __shfl_xor(rs, 1);
        rs += __shfl_xor(rs, 2);
        rs += __shfl_xor(rs, 4);
        rs += __shfl_xor(rs, 8);
        const float rv = fast_rcp(rs);
#pragma unroll
        for (int k = 0; k < 4; k++) {
            cp[k].x = fmaf(st[k].x, rv, cp[k].x);
            cp[k].y = fmaf(st[k].y, rv, cp[k].y);
            cp[k].z = fmaf(st[k].z, rv, cp[k].z);
            cp[k].w = fmaf(st[k].w, rv, cp[k].w);
        }
    }

    __syncthreads();  // acc init visible
#pragma unroll
    for (int k = 0; k < 4; k++) {
        atomicAdd(&acc[cg * 16 + k * 4 + 0], cp[k].x);
        atomicAdd(&acc[cg * 16 + k * 4 + 1], cp[k].y);
        atomicAdd(&acc[cg * 16 + k * 4 + 2], cp[k].z);
        atomicAdd(&acc[cg * 16 + k * 4 + 3], cp[k].w);
    }
    __syncthreads();
    Pbuf[(size_t)blockIdx.x * KCOLS + tid] = acc[tid];
}

// ---------------------------------------------------------------------------
// Final pass, slab-cooperative 256-thr blocks. Per-row argmax of E*g3 per half
// (identical u64 tie-break key), per-block best-row table -> Bbuf (no global
// atomics), GLU mix + L2-normalize epilogue (4 waves x 4 rows).
__global__ __launch_bounds__(256) void pass4_slab(const float* __restrict__ g3,
                                                  const float* __restrict__ x,
                                                  const float* __restrict__ gated,
                                                  float* __restrict__ outp, int nslabs) {
    __shared__ u64 bestL[2][SLAB_ROWS];
    __shared__ u64 bestG[2][SLAB_ROWS];
    __shared__ int blkBest[M_PROT];

    const int tid = threadIdx.x;
    const int lane = tid & 63;
    const int wave = tid >> 6;  // 0..3
    const int r16 = tid >> 4;   // row within slab 0..15
    const int cg = tid & 15;    // col-group: cols cg*16..cg*16+15

    if (tid < M_PROT) blkBest[tid] = -1;

    float4 cf[4];
    {
        const float4* g3v = (const float4*)g3;
#pragma unroll
        for (int k = 0; k < 4; k++) cf[k] = g3v[cg * 4 + k];
    }
    __syncthreads();  // blkBest init visible

    int it = 0;
    for (int slab = blockIdx.x; slab < nslabs; slab += gridDim.x, it++) {
        const int p = it & 1;
        float4 st[4];
        const float4* src = (const float4*)(Ebuf + (size_t)slab * SLAB_ROWS * KCOLS) + tid * 4;
#pragma unroll
        for (int k = 0; k < 4; k++) st[k] = src[k];

        // build this thread's best key over its 16 cols
        u64 key = 0;
        const int cb = cg * 16;
#pragma unroll
        for (int k = 0; k < 4; k++) {
            const float* ek = (const float*)&st[k];
            const float* ck = (const float*)&cf[k];
#pragma unroll
            for (int j = 0; j < 4; j++) {
                float v = ek[j] * ck[j];
                u64 kk = ((u64)__float_as_uint(v) << 32) | (u64)(255 - (cb + k * 4 + j));
                if (kk > key) key = kk;
            }
        }
        // reduce within 8-lane half-group (cg 0..7 = local cols, 8..15 = global)
        {
            u64 ok;
            ok = __shfl_xor((unsigned long long)key, 1); if (ok > key) key = ok;
            ok = __shfl_xor((unsigned long long)key, 2); if (ok > key) key = ok;
            ok = __shfl_xor((unsigned long long)key, 4); if (ok > key) key = ok;
        }
        if ((lane & 7) == 0) {
            if (cg < 8) bestL[p][r16] = key;
            else bestG[p][r16] = key;
        }
        __syncthreads();  // bests visible; parity-p slots are not rewritten
                          // until after the NEXT iteration's barrier

        if (tid < SLAB_ROWS) {
            int colL = 255 - (int)(bestL[p][tid] & 0xFFFFFFFFull);
            atomicMax(&blkBest[colL], slab * SLAB_ROWS + tid);  // LDS atomic
        }
#pragma unroll
        for (int rr = 0; rr < 4; rr++) {
            const int row = wave * 4 + rr;
            const int grow = slab * SLAB_ROWS + row;
            const float* xr = x + (size_t)grow * D_DIM;
            float x0 = xr[lane];
            float x1 = xr[lane + 64];
            float x2 = xr[lane + 128];
            const int ga = (255 - (int)(bestG[p][row] & 0xFFFFFFFFull)) - 128;
            const float* gr = gated + ga * D_DIM;
            float v0 = 0.5f * (gr[lane] + x0);
            float v1 = 0.5f * (gr[lane + 64] + x1);
            float v2 = 0.5f * (gr[lane + 128] + x2);
            float ss = v0 * v0;
            ss = fmaf(v1, v1, ss);
            ss = fmaf(v2, v2, ss);
            ss += __shfl_xor(ss, 1);
            ss += __shfl_xor(ss, 2);
            ss += __shfl_xor(ss, 4);
            ss += __shfl_xor(ss, 8);
            ss += __shfl_xor(ss, 16);
            ss += __shfl_xor(ss, 32);
            const float sc = newton_rsqrt(ss);
            float* orow = outp + (size_t)grow * D_DIM;
            orow[lane] = v0 * sc;
            orow[lane + 64] = v1 * sc;
            orow[lane + 128] = v2 * sc;
        }
    }

    __syncthreads();
    if (tid < M_PROT) Bbuf[(size_t)blockIdx.x * M_PROT + tid] = blkBest[tid];
}

// ---------------------------------------------------------------------------
// Merge per-block argmax candidates (max row index per proto) + EMA update.
__global__ __launch_bounds__(256) void final_local(const float* __restrict__ lp,
                                                   const float* __restrict__ x,
                                                   float* __restrict__ outL) {
    __shared__ int red[4];
    const int m = blockIdx.x;   // 128
    const int tid = threadIdx.x;
    const int lane = tid & 63;
    const int w = tid >> 6;
    int v = -1;
    for (int b = tid; b < GRID_SL; b += 256) {
        int c = Bbuf[(size_t)b * M_PROT + m];
        if (c > v) v = c;
    }
#pragma unroll
    for (int s = 1; s <= 32; s <<= 1) {
        int o = __shfl_xor(v, s);
        if (o > v) v = o;
    }
    if (lane == 0) red[w] = v;
    __syncthreads();
    int idx = max(max(red[0], red[1]), max(red[2], red[3]));
    if (tid < D_DIM) {
        float val = lp[m * D_DIM + tid];
        if (idx >= 0) val = 0.96f * val + (float)(1.0 - 0.96) * x[(size_t)idx * D_DIM + tid];
        outL[m * D_DIM + tid] = val;
    }
}

// ---------------------------------------------------------------------------
extern "C" void kernel_launch(void* const* d_in, const int* in_sizes, int n_in,
                              void* d_out, int out_size, void* d_ws, size_t ws_size,
                              hipStream_t stream) {
    const float* x = (const float*)d_in[0];
    const float* lp = (const float*)d_in[1];
    const float* gp = (const float*)d_in[2];
    const float* W = (const float*)d_in[3];
    const float* b = (const float*)d_in[4];
    float* out = (float*)d_out;
    const int nrows = in_sizes[0] / D_DIM;   // 131072
    const int nchunks = nrows / CHUNK_ROWS;  // 2048
    const int nslabs = nrows / SLAB_ROWS;    // 8192

    char* wsb = (char*)d_ws;
    float* invnp = (float*)(wsb + 0);
    float* g1 = (float*)(wsb + 1024);
    float* g2 = (float*)(wsb + 2048);
    float* g3 = (float*)(wsb + 3072);
    float* gated = (float*)(wsb + 8192);      // 128*192 f
    u16* phi = (u16*)(wsb + 106496);          // 256*192 u16
    u16* plo = (u16*)(wsb + 204800);          // 256*192 u16

    const uint4* phiv = (const uint4*)phi;
    const uint4* plov = (const uint4*)plo;

    prep_kern<<<256, 64, 0, stream>>>(lp, gp, phi, plo, invnp);
    glu_kern<<<128, 384, 0, stream>>>(gp, W, b, gated);
    pass1_kern<<<GRID_P, BLK, 0, stream>>>(x, phiv, plov, invnp, nchunks);
    reduce1<<<RED1_BLKS, 256, 0, stream>>>(GRID_P);
    reduce2<<<1, 256, 0, stream>>>(g1);
    sink_slab<<<GRID_SL, 256, 0, stream>>>(g1, nslabs);
    reduce1<<<RED1_BLKS, 256, 0, stream>>>(GRID_SL);
    reduce2<<<1, 256, 0, stream>>>(g2);
    sink_slab<<<GRID_SL, 256, 0, stream>>>(g2, nslabs);
    reduce1<<<RED1_BLKS, 256, 0, stream>>>(GRID_SL);
    reduce2<<<1, 256, 0, stream>>>(g3);
    pass4_slab<<<GRID_SL, 256, 0, stream>>>(g3, x, gated, out, nslabs);
    final_local<<<128, 256, 0, stream>>>(lp, x, out + (size_t)nrows * D_DIM);
}

// Round 7
// 419.795 us; speedup vs baseline: 1.6307x; 1.0172x over previous
//
#include <hip/hip_runtime.h>
#include <cstdint>

typedef unsigned short u16;
typedef unsigned long long u64;
typedef short short8 __attribute__((ext_vector_type(8)));
typedef float f32x4 __attribute__((ext_vector_type(4)));

#define D_DIM 192
#define M_PROT 128
#define KCOLS 256
#define GRID_P 256      // pass1: 1024-thr blocks -> 1/CU; grid = CU count
#define GRID_SL 2048    // slab kernels: 256-thr blocks, many blocks/CU
#define BLK 1024
#define CHUNK_ROWS 64
#define SLAB_ROWS 16    // pass4 slab
#define SSLAB_ROWS 32   // sink slab (2 rows/thread for ILP)
#define XSTRIDE 200   // u16 per x-row in LDS; 100 dwords -> 2-way banks on b128 reads (free)
#define NROWS_MAX 131072
#define RED1_BLKS 64

// Materialized E = exp(20 * cos_sim) matrix, row-major [N][256]. 128 MiB static
// device allocation (fits Infinity Cache; avoids ws_size assumptions, graph-safe).
__device__ float Ebuf[(size_t)NROWS_MAX * KCOLS];
// Per-block column partials + two-stage reduce intermediate.
__device__ float Pbuf[(size_t)GRID_SL * KCOLS];
__device__ float Mbuf[(size_t)RED1_BLKS * KCOLS];
// Per-block local-argmax "last row index" candidates (merged in final_local).
__device__ int Bbuf[(size_t)GRID_SL * M_PROT];

__device__ __forceinline__ float newton_rsqrt(float ss) {
    float m = fmaxf(ss, 1e-12f);
    float r = rsqrtf(m);
    r = r * (1.5f - 0.5f * m * r * r);
    return r;
}
__device__ __forceinline__ float fast_rcp(float x) {
    float r = __builtin_amdgcn_rcpf(x);
    return r * (2.0f - x * r);
}
// split fp32 -> bf16 hi (RNE) + bf16 lo (trunc of exact residual)
__device__ __forceinline__ void split1(float f, uint32_t& h, uint32_t& l) {
    uint32_t u = __float_as_uint(f);
    uint32_t uh = (u + 0x7FFFu + ((u >> 16) & 1u)) & 0xFFFF0000u;
    h = uh >> 16;
    l = __float_as_uint(f - __uint_as_float(uh)) >> 16;
}

// ---------------------------------------------------------------------------
__global__ void prep_kern(const float* __restrict__ lp, const float* __restrict__ gp,
                          u16* __restrict__ phi, u16* __restrict__ plo,
                          float* __restrict__ invnp) {
    int r = blockIdx.x, j = threadIdx.x;  // 256 x 64
    const float* src = (r < M_PROT) ? (lp + r * D_DIM) : (gp + (r - M_PROT) * D_DIM);
    float ss = 0.0f;
    for (int c = j; c < D_DIM; c += 64) {
        float f = src[c];
        ss = fmaf(f, f, ss);
        uint32_t h, l;
        split1(f, h, l);
        phi[r * D_DIM + c] = (u16)h;
        plo[r * D_DIM + c] = (u16)l;
    }
#pragma unroll
    for (int m = 1; m <= 32; m <<= 1) ss += __shfl_xor(ss, m);
    if (j == 0) invnp[r] = newton_rsqrt(ss);
}

// ---------------------------------------------------------------------------
__global__ __launch_bounds__(384) void glu_kern(const float* __restrict__ gp,
                                                const float* __restrict__ W,
                                                const float* __restrict__ b,
                                                float* __restrict__ gated) {
    __shared__ float grow[D_DIM];
    __shared__ float lin[2 * D_DIM];
    int m = blockIdx.x, j = threadIdx.x;
    if (j < D_DIM) grow[j] = gp[m * D_DIM + j];
    __syncthreads();
    float a = b[j];
    for (int k = 0; k < D_DIM; k++) a = fmaf(grow[k], W[k * 2 * D_DIM + j], a);
    lin[j] = a;
    __syncthreads();
    if (j < D_DIM) {
        float g = lin[j] * (1.0f / (1.0f + __expf(-lin[j + D_DIM])));
        gated[m * D_DIM + j] = g;
    }
}

// ---------------------------------------------------------------------------
// Two-stage parallel column reduce: Pbuf[0..G) -> Mbuf[64] -> outf (1/x).
__global__ __launch_bounds__(256) void reduce1(int G) {
    int j = threadIdx.x;
    float s = 0.0f;
    for (int g = blockIdx.x; g < G; g += RED1_BLKS) s += Pbuf[(size_t)g * KCOLS + j];
    Mbuf[blockIdx.x * KCOLS + j] = s;
}
__global__ __launch_bounds__(256) void reduce2(float* __restrict__ outf) {
    int j = threadIdx.x;
    float s = 0.0f;
    for (int g = 0; g < RED1_BLKS; g++) s += Mbuf[g * KCOLS + j];
    outf[j] = 1.0f / s;
}

// ---------------------------------------------------------------------------
// Pass 1: MFMA similarity + E = exp(20*sim), stored to Ebuf, fused with the
// first Sinkhorn colsum. Single-barrier pipeline: double-buffered x staging,
// 3-parity rsum rotation, colsum epilogue deferred one iteration (Eprev).
__global__ __launch_bounds__(BLK, 4) void pass1_kern(
    const float* __restrict__ x, const uint4* __restrict__ phiv, const uint4* __restrict__ plov,
    const float* __restrict__ invnp, int nchunks) {
    __shared__ u16 xhiS[2][CHUNK_ROWS * XSTRIDE];
    __shared__ u16 xloS[2][CHUNK_ROWS * XSTRIDE];
    __shared__ float xnv[2][CHUNK_ROWS];    // per-row inverse norm (rsqrt hoisted)
    __shared__ float rsum[3][CHUNK_ROWS];   // 3 parities: zero/accum/read barrier-separated

    const int tid = threadIdx.x;
    const int lane = tid & 63;
    const int wave = tid >> 6;        // 0..15: proto col-tile
    const int quad = lane >> 4;
    const int lcol = lane & 15;
    const int srow = tid >> 4;        // staging: row 0..63
    const int scg = tid & 15;         // staging: col-group (12 floats)

    // --- B fragments in registers: this wave's 16 proto cols, all K, hi+lo ---
    uint4 Bhi[6], Blo[6];
    {
        int prow = wave * 16 + lcol;
#pragma unroll
        for (int kk = 0; kk < 6; kk++) {
            int idx = prow * 24 + kk * 4 + quad;
            Bhi[kk] = phiv[idx];
            Blo[kk] = plov[idx];
        }
    }
    // fold 20 * log2(e) into the proto inv-norm: E = exp2(a * invnx * pnf20l2)
    const float pnf20l2 = invnp[wave * 16 + lcol] * 28.853900817779268f;
    float colpart = 0.0f;

    // prefetch chunk 0: 3 float4 = 12 contiguous cols of row srow
    float4 st[3];
    int chunk = blockIdx.x;
    if (chunk < nchunks) {
        const float4* src = (const float4*)(x + (size_t)chunk * CHUNK_ROWS * D_DIM +
                                            srow * D_DIM + scg * 12);
#pragma unroll
        for (int j = 0; j < 3; j++) st[j] = src[j];
    }

    f32x4 Ep[4];   // previous chunk's E (deferred epilogue)
    int it = 0;
    for (; chunk < nchunks; chunk += gridDim.x, it++) {
        const int b = it & 1;    // LDS staging buffer
        const int p = it % 3;    // rsum parity for THIS chunk
        // --- pre-barrier: zero this parity, stage chunk into buf b ---
        if (tid < CHUNK_ROWS) rsum[p][tid] = 0.0f;
        {
            float ssq = 0.0f;
            u16* bh = xhiS[b] + srow * XSTRIDE + scg * 12;
            u16* bl = xloS[b] + srow * XSTRIDE + scg * 12;
#pragma unroll
            for (int j = 0; j < 3; j++) {
                float4 v = st[j];
                ssq = fmaf(v.x, v.x, ssq);
                ssq = fmaf(v.y, v.y, ssq);
                ssq = fmaf(v.z, v.z, ssq);
                ssq = fmaf(v.w, v.w, ssq);
                uint32_t h0, l0, h1, l1, h2, l2, h3, l3;
                split1(v.x, h0, l0); split1(v.y, h1, l1);
                split1(v.z, h2, l2); split1(v.w, h3, l3);
                uint2 hp = {h0 | (h1 << 16), h2 | (h3 << 16)};
                uint2 lq = {l0 | (l1 << 16), l2 | (l3 << 16)};
                *(uint2*)(bh + j * 4) = hp;
                *(uint2*)(bl + j * 4) = lq;
            }
            ssq += __shfl_xor(ssq, 1);
            ssq += __shfl_xor(ssq, 2);
            ssq += __shfl_xor(ssq, 4);
            ssq += __shfl_xor(ssq, 8);
            if (scg == 0) xnv[b][srow] = newton_rsqrt(ssq);
        }
        {   // prefetch next chunk while this one computes
            int nc = chunk + gridDim.x;
            if (nc < nchunks) {
                const float4* src = (const float4*)(x + (size_t)nc * CHUNK_ROWS * D_DIM +
                                                    srow * D_DIM + scg * 12);
#pragma unroll
                for (int j = 0; j < 3; j++) st[j] = src[j];
            }
        }
        __syncthreads();  // single barrier: staging(b) visible; rsum[(it-1)%3] complete

        // --- deferred colsum epilogue for chunk it-1 ---
        if (it > 0) {
            const int pp = (p + 2) % 3;  // == (it-1)%3
#pragma unroll
            for (int s = 0; s < 4; s++) {
                const int rowb = s * 16 + quad * 4;
#pragma unroll
                for (int r = 0; r < 4; r++)
                    colpart = fmaf(Ep[s][r], fast_rcp(rsum[pp][rowb + r]), colpart);
            }
        }

        f32x4 E[4];
#pragma unroll
        for (int s = 0; s < 4; s++) {
            f32x4 a0 = {}, a1 = {};
#pragma unroll
            for (int kk = 0; kk < 6; kk++) {
                int off = (s * 16 + lcol) * XSTRIDE + kk * 32 + quad * 8;
                uint4 hraw = *(const uint4*)(xhiS[b] + off);
                uint4 lraw = *(const uint4*)(xloS[b] + off);
                short8 ah = __builtin_bit_cast(short8, hraw);
                short8 al = __builtin_bit_cast(short8, lraw);
                short8 bh = __builtin_bit_cast(short8, Bhi[kk]);
                short8 bl = __builtin_bit_cast(short8, Blo[kk]);
                if (kk & 1) {
                    a1 = __builtin_amdgcn_mfma_f32_16x16x32_bf16(ah, bh, a1, 0, 0, 0);
                    a1 = __builtin_amdgcn_mfma_f32_16x16x32_bf16(ah, bl, a1, 0, 0, 0);
                    a1 = __builtin_amdgcn_mfma_f32_16x16x32_bf16(al, bh, a1, 0, 0, 0);
                } else {
                    a0 = __builtin_amdgcn_mfma_f32_16x16x32_bf16(ah, bh, a0, 0, 0, 0);
                    a0 = __builtin_amdgcn_mfma_f32_16x16x32_bf16(ah, bl, a0, 0, 0, 0);
                    a0 = __builtin_amdgcn_mfma_f32_16x16x32_bf16(al, bh, a0, 0, 0, 0);
                }
            }
            const int rowb = s * 16 + quad * 4;
#pragma unroll
            for (int r = 0; r < 4; r++)
                E[s][r] = exp2f((a0[r] + a1[r]) * xnv[b][rowb + r] * pnf20l2);
            // store E tile to global (row-major [N][256]); fire-and-forget
            {
                float* eb = Ebuf + ((size_t)chunk * CHUNK_ROWS + rowb) * KCOLS +
                            (wave * 16 + lcol);
#pragma unroll
                for (int r = 0; r < 4; r++) eb[r * KCOLS] = E[s][r];
            }
#pragma unroll
            for (int r = 0; r < 4; r++) {
                float pe = E[s][r];
                pe += __shfl_xor(pe, 1);
                pe += __shfl_xor(pe, 2);
                pe += __shfl_xor(pe, 4);
                pe += __shfl_xor(pe, 8);
                if (lcol == 0) atomicAdd(&rsum[p][rowb + r], pe);
            }
        }
#pragma unroll
        for (int s = 0; s < 4; s++) Ep[s] = E[s];
    }

    // final deferred epilogue for the last chunk
    __syncthreads();
    {
        const int pl = (it + 2) % 3;  // == (it-1)%3
#pragma unroll
        for (int s = 0; s < 4; s++) {
            const int rowb = s * 16 + quad * 4;
#pragma unroll
            for (int r = 0; r < 4; r++)
                colpart = fmaf(Ep[s][r], fast_rcp(rsum[pl][rowb + r]), colpart);
        }
    }

    colpart += __shfl_xor(colpart, 16);
    colpart += __shfl_xor(colpart, 32);
    if (lane < 16) Pbuf[(size_t)blockIdx.x * KCOLS + wave * 16 + lcol] = colpart;
}

// ---------------------------------------------------------------------------
// Sinkhorn iteration, 32-row slabs, 2 rows/thread (8 loads in flight for ILP).
// Thread t owns rows (t>>4) and (t>>4)+16, cols (t&15)*16..+15.
__global__ __launch_bounds__(256) void sink_slab(const float* __restrict__ w,
                                                 int nslabs32) {
    __shared__ float acc[KCOLS];
    const int tid = threadIdx.x;
    const int cg = tid & 15;
    acc[tid] = 0.0f;

    float4 wv[4];
    {
        const float4* wvp = (const float4*)w;
#pragma unroll
        for (int k = 0; k < 4; k++) wv[k] = wvp[cg * 4 + k];
    }
    float4 cp[4];
#pragma unroll
    for (int k = 0; k < 4; k++) { cp[k].x = 0.f; cp[k].y = 0.f; cp[k].z = 0.f; cp[k].w = 0.f; }

    for (int slab = blockIdx.x; slab < nslabs32; slab += gridDim.x) {
        const float* base = Ebuf + (size_t)slab * SSLAB_ROWS * KCOLS;
        const float4* s0 = (const float4*)base + tid * 4;
        const float4* s1 = (const float4*)(base + 16 * KCOLS) + tid * 4;
        float4 sa[4], sb[4];
#pragma unroll
        for (int k = 0; k < 4; k++) sa[k] = s0[k];
#pragma unroll
        for (int k = 0; k < 4; k++) sb[k] = s1[k];

        float rs0 = 0.0f, rs1 = 0.0f;
#pragma unroll
        for (int k = 0; k < 4; k++) {
            rs0 = fmaf(sa[k].x, wv[k].x, rs0);
            rs0 = fmaf(sa[k].y, wv[k].y, rs0);
            rs0 = fmaf(sa[k].z, wv[k].z, rs0);
            rs0 = fmaf(sa[k].w, wv[k].w, rs0);
            rs1 = fmaf(sb[k].x, wv[k].x, rs1);
            rs1 = fmaf(sb[k].y, wv[k].y, rs1);
            rs1 = fmaf(sb[k].z, wv[k].z, rs1);
            rs1 = fmaf(sb[k].w, wv[k].w, rs1);
        }
        // reduce across the 16 threads owning each row (16-lane subgroups)
        rs0 += __shfl_xor(rs0, 1);
        rs1 += __shfl_xor(rs1, 1);
        rs0 += __shfl_xor(rs0, 2);
        rs1 += __shfl_xor(rs1, 2);
        rs0 += __shfl_xor(rs0, 4);
        rs1 += __shfl_xor(rs1, 4);
        rs0 += __shfl_xor(rs0, 8);
        rs1 += __shfl_xor(rs1, 8);
        const float rv0 = fast_rcp(rs0);
        const float rv1 = fast_rcp(rs1);
#pragma unroll
        for (int k = 0; k < 4; k++) {
            cp[k].x = fmaf(sa[k].x, rv0, cp[k].x);
            cp[k].y = fmaf(sa[k].y, rv0, cp[k].y);
            cp[k].z = fmaf(sa[k].z, rv0, cp[k].z);
            cp[k].w = fmaf(sa[k].w, rv0, cp[k].w);
            cp[k].x = fmaf(sb[k].x, rv1, cp[k].x);
            cp[k].y = fmaf(sb[k].y, rv1, cp[k].y);
            cp[k].z = fmaf(sb[k].z, rv1, cp[k].z);
            cp[k].w = fmaf(sb[k].w, rv1, cp[k].w);
        }
    }

    __syncthreads();  // acc init visible
#pragma unroll
    for (int k = 0; k < 4; k++) {
        atomicAdd(&acc[cg * 16 + k * 4 + 0], cp[k].x);
        atomicAdd(&acc[cg * 16 + k * 4 + 1], cp[k].y);
        atomicAdd(&acc[cg * 16 + k * 4 + 2], cp[k].z);
        atomicAdd(&acc[cg * 16 + k * 4 + 3], cp[k].w);
    }
    __syncthreads();
    Pbuf[(size_t)blockIdx.x * KCOLS + tid] = acc[tid];
}

// ---------------------------------------------------------------------------
// Final pass, slab-cooperative 256-thr blocks. Per-row argmax of E*g3 per half
// (identical u64 tie-break key), per-block best-row table -> Bbuf (no global
// atomics), GLU mix + L2-normalize epilogue (4 waves x 4 rows).
__global__ __launch_bounds__(256) void pass4_slab(const float* __restrict__ g3,
                                                  const float* __restrict__ x,
                                                  const float* __restrict__ gated,
                                                  float* __restrict__ outp, int nslabs) {
    __shared__ u64 bestL[2][SLAB_ROWS];
    __shared__ u64 bestG[2][SLAB_ROWS];
    __shared__ int blkBest[M_PROT];

    const int tid = threadIdx.x;
    const int lane = tid & 63;
    const int wave = tid >> 6;  // 0..3
    const int r16 = tid >> 4;   // row within slab 0..15
    const int cg = tid & 15;    // col-group: cols cg*16..cg*16+15

    if (tid < M_PROT) blkBest[tid] = -1;

    float4 cf[4];
    {
        const float4* g3v = (const float4*)g3;
#pragma unroll
        for (int k = 0; k < 4; k++) cf[k] = g3v[cg * 4 + k];
    }
    __syncthreads();  // blkBest init visible

    int it = 0;
    for (int slab = blockIdx.x; slab < nslabs; slab += gridDim.x, it++) {
        const int p = it & 1;
        float4 st[4];
        const float4* src = (const float4*)(Ebuf + (size_t)slab * SLAB_ROWS * KCOLS) + tid * 4;
#pragma unroll
        for (int k = 0; k < 4; k++) st[k] = src[k];

        // build this thread's best key over its 16 cols
        u64 key = 0;
        const int cb = cg * 16;
#pragma unroll
        for (int k = 0; k < 4; k++) {
            const float* ek = (const float*)&st[k];
            const float* ck = (const float*)&cf[k];
#pragma unroll
            for (int j = 0; j < 4; j++) {
                float v = ek[j] * ck[j];
                u64 kk = ((u64)__float_as_uint(v) << 32) | (u64)(255 - (cb + k * 4 + j));
                if (kk > key) key = kk;
            }
        }
        // reduce within 8-lane half-group (cg 0..7 = local cols, 8..15 = global)
        {
            u64 ok;
            ok = __shfl_xor((unsigned long long)key, 1); if (ok > key) key = ok;
            ok = __shfl_xor((unsigned long long)key, 2); if (ok > key) key = ok;
            ok = __shfl_xor((unsigned long long)key, 4); if (ok > key) key = ok;
        }
        if ((lane & 7) == 0) {
            if (cg < 8) bestL[p][r16] = key;
            else bestG[p][r16] = key;
        }
        __syncthreads();  // bests visible; parity-p slots are not rewritten
                          // until after the NEXT iteration's barrier

        if (tid < SLAB_ROWS) {
            int colL = 255 - (int)(bestL[p][tid] & 0xFFFFFFFFull);
            atomicMax(&blkBest[colL], slab * SLAB_ROWS + tid);  // LDS atomic
        }
#pragma unroll
        for (int rr = 0; rr < 4; rr++) {
            const int row = wave * 4 + rr;
            const int grow = slab * SLAB_ROWS + row;
            const float* xr = x + (size_t)grow * D_DIM;
            float x0 = xr[lane];
            float x1 = xr[lane + 64];
            float x2 = xr[lane + 128];
            const int ga = (255 - (int)(bestG[p][row] & 0xFFFFFFFFull)) - 128;
            const float* gr = gated + ga * D_DIM;
            float v0 = 0.5f * (gr[lane] + x0);
            float v1 = 0.5f * (gr[lane + 64] + x1);
            float v2 = 0.5f * (gr[lane + 128] + x2);
            float ss = v0 * v0;
            ss = fmaf(v1, v1, ss);
            ss = fmaf(v2, v2, ss);
            ss += __shfl_xor(ss, 1);
            ss += __shfl_xor(ss, 2);
            ss += __shfl_xor(ss, 4);
            ss += __shfl_xor(ss, 8);
            ss += __shfl_xor(ss, 16);
            ss += __shfl_xor(ss, 32);
            const float sc = newton_rsqrt(ss);
            float* orow = outp + (size_t)grow * D_DIM;
            orow[lane] = v0 * sc;
            orow[lane + 64] = v1 * sc;
            orow[lane + 128] = v2 * sc;
        }
    }

    __syncthreads();
    if (tid < M_PROT) Bbuf[(size_t)blockIdx.x * M_PROT + tid] = blkBest[tid];
}

// ---------------------------------------------------------------------------
// Merge per-block argmax candidates (max row index per proto) + EMA update.
__global__ __launch_bounds__(256) void final_local(const float* __restrict__ lp,
                                                   const float* __restrict__ x,
                                                   float* __restrict__ outL) {
    __shared__ int red[4];
    const int m = blockIdx.x;   // 128
    const int tid = threadIdx.x;
    const int lane = tid & 63;
    const int w = tid >> 6;
    int v = -1;
    for (int b = tid; b < GRID_SL; b += 256) {
        int c = Bbuf[(size_t)b * M_PROT + m];
        if (c > v) v = c;
    }
#pragma unroll
    for (int s = 1; s <= 32; s <<= 1) {
        int o = __shfl_xor(v, s);
        if (o > v) v = o;
    }
    if (lane == 0) red[w] = v;
    __syncthreads();
    int idx = max(max(red[0], red[1]), max(red[2], red[3]));
    if (tid < D_DIM) {
        float val = lp[m * D_DIM + tid];
        if (idx >= 0) val = 0.96f * val + (float)(1.0 - 0.96) * x[(size_t)idx * D_DIM + tid];
        outL[m * D_DIM + tid] = val;
    }
}

// ---------------------------------------------------------------------------
extern "C" void kernel_launch(void* const* d_in, const int* in_sizes, int n_in,
                              void* d_out, int out_size, void* d_ws, size_t ws_size,
                              hipStream_t stream) {
    const float* x = (const float*)d_in[0];
    const float* lp = (const float*)d_in[1];
    const float* gp = (const float*)d_in[2];
    const float* W = (const float*)d_in[3];
    const float* b = (const float*)d_in[4];
    float* out = (float*)d_out;
    const int nrows = in_sizes[0] / D_DIM;   // 131072
    const int nchunks = nrows / CHUNK_ROWS;  // 2048
    const int nslabs = nrows / SLAB_ROWS;    // 8192
    const int nslabs32 = nrows / SSLAB_ROWS; // 4096

    char* wsb = (char*)d_ws;
    float* invnp = (float*)(wsb + 0);
    float* g1 = (float*)(wsb + 1024);
    float* g2 = (float*)(wsb + 2048);
    float* g3 = (float*)(wsb + 3072);
    float* gated = (float*)(wsb + 8192);      // 128*192 f
    u16* phi = (u16*)(wsb + 106496);          // 256*192 u16
    u16* plo = (u16*)(wsb + 204800);          // 256*192 u16

    const uint4* phiv = (const uint4*)phi;
    const uint4* plov = (const uint4*)plo;

    prep_kern<<<256, 64, 0, stream>>>(lp, gp, phi, plo, invnp);
    glu_kern<<<128, 384, 0, stream>>>(gp, W, b, gated);
    pass1_kern<<<GRID_P, BLK, 0, stream>>>(x, phiv, plov, invnp, nchunks);
    reduce1<<<RED1_BLKS, 256, 0, stream>>>(GRID_P);
    reduce2<<<1, 256, 0, stream>>>(g1);
    sink_slab<<<GRID_SL, 256, 0, stream>>>(g1, nslabs32);
    reduce1<<<RED1_BLKS, 256, 0, stream>>>(GRID_SL);
    reduce2<<<1, 256, 0, stream>>>(g2);
    sink_slab<<<GRID_SL, 256, 0, stream>>>(g2, nslabs32);
    reduce1<<<RED1_BLKS, 256, 0, stream>>>(GRID_SL);
    reduce2<<<1, 256, 0, stream>>>(g3);
    pass4_slab<<<GRID_SL, 256, 0, stream>>>(g3, x, gated, out, nslabs);
    final_local<<<128, 256, 0, stream>>>(lp, x, out + (size_t)nrows * D_DIM);
}